// Round 3
// baseline (251.239 us; speedup 1.0000x reference)
//
#include <hip/hip_runtime.h>

typedef __attribute__((ext_vector_type(8))) _Float16 half8;  // 8 x fp16 (MFMA A/B frag)
typedef __attribute__((ext_vector_type(4))) float f32x4;     // MFMA C/D frag
typedef __attribute__((ext_vector_type(2))) float f32x2;
typedef __attribute__((ext_vector_type(2))) unsigned int uint2v;

#define LOG2E 1.44269504088896340736f

__device__ __forceinline__ unsigned short f2h(float x) {
  _Float16 h = (_Float16)x;  // RNE
  union { _Float16 h; unsigned short u; } v; v.h = h;
  return v.u;
}
__device__ __forceinline__ float h2f(unsigned short u) {
  union { unsigned short u; _Float16 h; } v; v.u = u;
  return (float)v.h;
}

// ---------------------------------------------------------------------------
// Kernel 0: pack weights: WT[w][n][k] = fp16(W_w[k][n]),  w in {q,k,v}
// ---------------------------------------------------------------------------
__global__ __launch_bounds__(256) void pack_w(
    const float* __restrict__ Wq, const float* __restrict__ Wk,
    const float* __restrict__ Wv, unsigned short* __restrict__ WT) {
  int idx = blockIdx.x * 256 + threadIdx.x;  // 3*128*256 = 98304 total
  int w = idx >> 15;
  int r = idx & 32767;
  int n = r >> 8;   // out feature
  int k = r & 255;  // in feature
  const float* W = (w == 0) ? Wq : ((w == 1) ? Wk : Wv);
  WT[idx] = f2h(W[k * 128 + n]);
}

// ---------------------------------------------------------------------------
// Kernel 1: projections, 1-wave blocks, barrier-free, weights from L2.
// Each wave: 16 rows of X (A-frags in regs), full K=256, all 3 outputs.
// grid = 16384/16 = 1024 blocks x 64 threads.
// ---------------------------------------------------------------------------
__global__ __launch_bounds__(64) void proj1(
    const float* __restrict__ seq, const unsigned short* __restrict__ WT,
    unsigned short* __restrict__ Qb, unsigned short* __restrict__ Kb,
    unsigned short* __restrict__ VTb) {
  const int lane = threadIdx.x & 63, lo = lane & 15, hi = lane >> 4;
  const int qb = blockIdx.x * 16;

  half8 a[8];
#pragma unroll
  for (int kb = 0; kb < 8; ++kb) {
    const float* p = &seq[(qb + lo) * 256 + kb * 32 + hi * 8];
    f32x4 x0 = *reinterpret_cast<const f32x4*>(p);
    f32x4 x1 = *reinterpret_cast<const f32x4*>(p + 4);
    half8 v;
    v[0] = (_Float16)x0[0]; v[1] = (_Float16)x0[1];
    v[2] = (_Float16)x0[2]; v[3] = (_Float16)x0[3];
    v[4] = (_Float16)x1[0]; v[5] = (_Float16)x1[1];
    v[6] = (_Float16)x1[2]; v[7] = (_Float16)x1[3];
    a[kb] = v;
  }

  f32x4 aq[8], ak[8], av[8];
  const f32x4 z = {0.f, 0.f, 0.f, 0.f};
#pragma unroll
  for (int e = 0; e < 8; ++e) { aq[e] = z; ak[e] = z; av[e] = z; }

#pragma unroll
  for (int kb = 0; kb < 8; ++kb) {
#pragma unroll
    for (int e8 = 0; e8 < 8; ++e8) {
      const int wrow = (e8 * 16 + lo) * 256 + kb * 32 + hi * 8;
      half8 bq = *reinterpret_cast<const half8*>(&WT[wrow]);
      half8 bk = *reinterpret_cast<const half8*>(&WT[32768 + wrow]);
      half8 bv = *reinterpret_cast<const half8*>(&WT[65536 + wrow]);
      aq[e8] = __builtin_amdgcn_mfma_f32_16x16x32_f16(a[kb], bq, aq[e8], 0, 0, 0);
      ak[e8] = __builtin_amdgcn_mfma_f32_16x16x32_f16(a[kb], bk, ak[e8], 0, 0, 0);
      av[e8] = __builtin_amdgcn_mfma_f32_16x16x32_f16(bv, a[kb], av[e8], 0, 0, 0);
    }
  }
  // C/D layout: col = lane&15, row = (lane>>4)*4 + i
#pragma unroll
  for (int e8 = 0; e8 < 8; ++e8) {
#pragma unroll
    for (int i = 0; i < 4; ++i) {
      int row = qb + hi * 4 + i;
      int col = e8 * 16 + lo;
      Qb[row * 128 + col] = f2h(aq[e8][i]);
      Kb[row * 128 + col] = f2h(ak[e8][i]);
      VTb[(e8 * 16 + hi * 4 + i) * 16384 + qb + lo] = f2h(av[e8][i]);
    }
  }
}

// ---------------------------------------------------------------------------
// Kernel 2: KV-split flash attention. NSPLIT=4 (1024 keys/block).
// Block: 128 thr = 2 waves; 32 q-rows/wave (64/block); KVBLK=64.
// K staged in LDS (shared by both waves); V read direct from VTb (L2);
// P per-wave in LDS. Partials (O fp16, m, l) to workspace.
// grid = 256 qtiles * 4 splits = 1024; swizzle: blk = t*16 + c, c=(b,s).
// ---------------------------------------------------------------------------
__global__ __launch_bounds__(128) void attn_split(
    const unsigned short* __restrict__ Qb, const unsigned short* __restrict__ Kb,
    const unsigned short* __restrict__ VTb, unsigned short* __restrict__ Opart,
    float* __restrict__ ml) {
  __shared__ unsigned short K_lds[64 * 136];     // 64 kv x 128 feat (+8 pad)
  __shared__ unsigned short P_lds[2 * 32 * 72];  // per-wave 32 q x 64 kv (+8 pad)

  const int tid = threadIdx.x;
  const int wv = tid >> 6, lane = tid & 63, lo = lane & 15, hi = lane >> 4;
  const int c = blockIdx.x & 15, t = blockIdx.x >> 4;  // t in [0,64)
  const int b = c >> 2, s = c & 3;
  const int qt = b * 64 + t;                 // global 64-row q-tile [0,256)
  const int qrow = b * 4096 + t * 64 + wv * 32;
  const int kv0 = b * 4096 + s * 1024;

  half8 qf[2][4];
#pragma unroll
  for (int h = 0; h < 2; ++h)
#pragma unroll
    for (int kc = 0; kc < 4; ++kc)
      qf[h][kc] = *reinterpret_cast<const half8*>(
          &Qb[(qrow + h * 16 + lo) * 128 + kc * 32 + hi * 8]);

  f32x4 acc[2][8];
  const f32x4 z = {0.f, 0.f, 0.f, 0.f};
#pragma unroll
  for (int h = 0; h < 2; ++h)
#pragma unroll
    for (int e = 0; e < 8; ++e) acc[h][e] = z;
  float m[2] = {-INFINITY, -INFINITY}, l[2] = {0.f, 0.f};
  unsigned short* Pw = &P_lds[wv * 32 * 72];

  for (int kt = 0; kt < 16; ++kt) {
    const int kvb = kv0 + kt * 64;
    __syncthreads();  // prev tile's K_lds reads complete
#pragma unroll
    for (int i = tid; i < 1024; i += 128) {
      int row = i >> 4, ch = i & 15;
      *reinterpret_cast<half8*>(&K_lds[row * 136 + ch * 8]) =
          *reinterpret_cast<const half8*>(&Kb[(kvb + row) * 128 + ch * 8]);
    }
    __syncthreads();

    // S^T = K * Q^T for both q-halves (K-frag reused)
    f32x4 sf0[4], sf1[4];
#pragma unroll
    for (int f = 0; f < 4; ++f) { sf0[f] = z; sf1[f] = z; }
#pragma unroll
    for (int f = 0; f < 4; ++f) {
#pragma unroll
      for (int kc = 0; kc < 4; ++kc) {
        half8 akf = *reinterpret_cast<const half8*>(
            &K_lds[(f * 16 + lo) * 136 + kc * 32 + hi * 8]);
        sf0[f] = __builtin_amdgcn_mfma_f32_16x16x32_f16(akf, qf[0][kc], sf0[f], 0, 0, 0);
        sf1[f] = __builtin_amdgcn_mfma_f32_16x16x32_f16(akf, qf[1][kc], sf1[f], 0, 0, 0);
      }
    }

    // online softmax per half (each lane owns q-row lo of its half)
#pragma unroll
    for (int h = 0; h < 2; ++h) {
      f32x4* sfh = h ? sf1 : sf0;
      float tmax = -INFINITY;
#pragma unroll
      for (int f = 0; f < 4; ++f)
#pragma unroll
        for (int i = 0; i < 4; ++i) tmax = fmaxf(tmax, sfh[f][i]);
      tmax = fmaxf(tmax, __shfl_xor(tmax, 16, 64));
      tmax = fmaxf(tmax, __shfl_xor(tmax, 32, 64));
      float mn = fmaxf(m[h], tmax);
      float alpha = exp2f((m[h] - mn) * LOG2E);
      float ts = 0.f;
#pragma unroll
      for (int f = 0; f < 4; ++f)
#pragma unroll
        for (int i = 0; i < 4; ++i) {
          float p = exp2f((sfh[f][i] - mn) * LOG2E);
          sfh[f][i] = p;
          ts += p;
        }
      ts += __shfl_xor(ts, 16, 64);
      ts += __shfl_xor(ts, 32, 64);
      l[h] = l[h] * alpha + ts;
      m[h] = mn;
      // P -> per-wave LDS (A-frag layout)
#pragma unroll
      for (int f = 0; f < 4; ++f) {
        uint2v pk;
        pk[0] = (unsigned)f2h(sfh[f][0]) | ((unsigned)f2h(sfh[f][1]) << 16);
        pk[1] = (unsigned)f2h(sfh[f][2]) | ((unsigned)f2h(sfh[f][3]) << 16);
        *reinterpret_cast<uint2v*>(&Pw[(h * 16 + lo) * 72 + f * 16 + hi * 4]) = pk;
      }
      float a0 = __shfl(alpha, hi * 4 + 0, 64);
      float a1 = __shfl(alpha, hi * 4 + 1, 64);
      float a2 = __shfl(alpha, hi * 4 + 2, 64);
      float a3 = __shfl(alpha, hi * 4 + 3, 64);
#pragma unroll
      for (int e8 = 0; e8 < 8; ++e8) {
        acc[h][e8][0] *= a0; acc[h][e8][1] *= a1;
        acc[h][e8][2] *= a2; acc[h][e8][3] *= a3;
      }
    }

    // O += P * V ; V B-frags direct from global (L2-resident), reused by halves
#pragma unroll
    for (int f2 = 0; f2 < 2; ++f2) {
      half8 pa0 = *reinterpret_cast<const half8*>(&Pw[lo * 72 + f2 * 32 + hi * 8]);
      half8 pa1 = *reinterpret_cast<const half8*>(&Pw[(16 + lo) * 72 + f2 * 32 + hi * 8]);
#pragma unroll
      for (int e8 = 0; e8 < 8; ++e8) {
        half8 bv = *reinterpret_cast<const half8*>(
            &VTb[(e8 * 16 + lo) * 16384 + kvb + f2 * 32 + hi * 8]);
        acc[0][e8] = __builtin_amdgcn_mfma_f32_16x16x32_f16(pa0, bv, acc[0][e8], 0, 0, 0);
        acc[1][e8] = __builtin_amdgcn_mfma_f32_16x16x32_f16(pa1, bv, acc[1][e8], 0, 0, 0);
      }
    }
  }

  // partial epilogue: Opart[(qt*4+s)*64 + rl][col] fp16, ml[(qt*4+s)*64+rl]
  const int pbase = (qt * 4 + s) * 64;
#pragma unroll
  for (int h = 0; h < 2; ++h) {
#pragma unroll
    for (int e8 = 0; e8 < 8; ++e8)
#pragma unroll
      for (int i = 0; i < 4; ++i) {
        int rl = wv * 32 + h * 16 + hi * 4 + i;
        Opart[(pbase + rl) * 128 + e8 * 16 + lo] = f2h(acc[h][e8][i]);
      }
    if (hi == 0) {
      f32x2 v; v[0] = m[h]; v[1] = l[h];
      *reinterpret_cast<f32x2*>(&ml[(pbase + wv * 32 + h * 16 + lo) * 2]) = v;
    }
  }
}

// ---------------------------------------------------------------------------
// Kernel 3: merge NSPLIT=4 partials.
// ---------------------------------------------------------------------------
__global__ __launch_bounds__(256) void merge_kernel(
    const unsigned short* __restrict__ Opart, const float* __restrict__ ml,
    float* __restrict__ out) {
  int idx = blockIdx.x * 256 + threadIdx.x;  // 16384*128 = 2097152
  int r = idx >> 7, col = idx & 127;
  int qt = r >> 6, rl = r & 63;
  float mm[4], ll[4];
#pragma unroll
  for (int s = 0; s < 4; ++s) {
    f32x2 v = *reinterpret_cast<const f32x2*>(&ml[((qt * 4 + s) * 64 + rl) * 2]);
    mm[s] = v[0]; ll[s] = v[1];
  }
  float M = fmaxf(fmaxf(mm[0], mm[1]), fmaxf(mm[2], mm[3]));
  float L = 0.f, o = 0.f;
#pragma unroll
  for (int s = 0; s < 4; ++s) {
    float w = exp2f((mm[s] - M) * LOG2E);
    L += w * ll[s];
    o += w * h2f(Opart[((qt * 4 + s) * 64 + rl) * 128 + col]);
  }
  out[r * 128 + col] = o / L;
}

// ---------------------------------------------------------------------------
extern "C" void kernel_launch(void* const* d_in, const int* in_sizes, int n_in,
                              void* d_out, int out_size, void* d_ws, size_t ws_size,
                              hipStream_t stream) {
  const float* seq = (const float*)d_in[0];
  // d_in[1] = lengths: UNUSED by the reference (no masking).
  const float* Wq = (const float*)d_in[2];
  const float* Wk = (const float*)d_in[3];
  const float* Wv = (const float*)d_in[4];
  float* out = (float*)d_out;

  unsigned short* WT  = (unsigned short*)d_ws;       // 98304 halfs
  unsigned short* Qb  = WT + 3 * 128 * 256;          // 16384*128
  unsigned short* Kb  = Qb + 16384 * 128;
  unsigned short* VTb = Kb + 16384 * 128;
  unsigned short* Opart = VTb + 16384 * 128;         // 256*4*64*128 halfs = 16.78MB
  float* ml = (float*)(Opart + 256 * 4 * 64 * 128);  // 65536 float2 = 512KB

  pack_w<<<384, 256, 0, stream>>>(Wq, Wk, Wv, WT);
  proj1<<<1024, 64, 0, stream>>>(seq, WT, Qb, Kb, VTb);
  attn_split<<<1024, 128, 0, stream>>>(Qb, Kb, VTb, Opart, ml);
  merge_kernel<<<8192, 256, 0, stream>>>(Opart, ml, out);
}

// Round 4
// 98.817 us; speedup vs baseline: 2.5425x; 2.5425x over previous
//
#include <hip/hip_runtime.h>

typedef __attribute__((ext_vector_type(8))) _Float16 half8;   // MFMA A/B frag (4 VGPR)
typedef __attribute__((ext_vector_type(16))) float f32x16;    // 32x32 MFMA C/D frag
typedef __attribute__((ext_vector_type(4))) float f32x4;
typedef __attribute__((ext_vector_type(2))) float f32x2;
typedef __attribute__((ext_vector_type(2))) unsigned int uint2v;
typedef __attribute__((ext_vector_type(4))) unsigned int uint4v;

#define LOG2E 1.44269504088896340736f
#define NKT 16  // kv tiles of 64 per split (4096/4/64)

__device__ __forceinline__ unsigned short f2h(float x) {
  _Float16 h = (_Float16)x;
  union { _Float16 h; unsigned short u; } v; v.h = h;
  return v.u;
}
__device__ __forceinline__ float h2f(unsigned short u) {
  union { unsigned short u; _Float16 h; } v; v.u = u;
  return (float)v.h;
}
__device__ __forceinline__ unsigned pk2(float a, float b) {  // pack 2 f32 -> 2 f16 (RTZ)
  auto h = __builtin_amdgcn_cvt_pkrtz(a, b);
  return __builtin_bit_cast(unsigned, h);
}

// ---------------------------------------------------------------------------
// Kernel 0: pack weights: WT[w][n][k] = fp16(W_w[k][n])
// ---------------------------------------------------------------------------
__global__ __launch_bounds__(256) void pack_w(
    const float* __restrict__ Wq, const float* __restrict__ Wk,
    const float* __restrict__ Wv, unsigned short* __restrict__ WT) {
  int idx = blockIdx.x * 256 + threadIdx.x;
  int w = idx >> 15;
  int r = idx & 32767;
  int n = r >> 8;
  int k = r & 255;
  const float* W = (w == 0) ? Wq : ((w == 1) ? Wk : Wv);
  WT[idx] = f2h(W[k * 128 + n]);
}

// ---------------------------------------------------------------------------
// Kernel 1: projections, 1-wave blocks, barrier-free, weights from L2.
// ---------------------------------------------------------------------------
__global__ __launch_bounds__(64) void proj1(
    const float* __restrict__ seq, const unsigned short* __restrict__ WT,
    unsigned short* __restrict__ Qb, unsigned short* __restrict__ Kb,
    unsigned short* __restrict__ VTb) {
  const int lane = threadIdx.x & 63, lo = lane & 15, hi = lane >> 4;
  const int qb = blockIdx.x * 16;

  half8 a[8];
#pragma unroll
  for (int kb = 0; kb < 8; ++kb) {
    const float* p = &seq[(qb + lo) * 256 + kb * 32 + hi * 8];
    f32x4 x0 = *reinterpret_cast<const f32x4*>(p);
    f32x4 x1 = *reinterpret_cast<const f32x4*>(p + 4);
    half8 v;
    v[0] = (_Float16)x0[0]; v[1] = (_Float16)x0[1];
    v[2] = (_Float16)x0[2]; v[3] = (_Float16)x0[3];
    v[4] = (_Float16)x1[0]; v[5] = (_Float16)x1[1];
    v[6] = (_Float16)x1[2]; v[7] = (_Float16)x1[3];
    a[kb] = v;
  }

  f32x4 aq[8], ak[8], av[8];
  const f32x4 z = {0.f, 0.f, 0.f, 0.f};
#pragma unroll
  for (int e = 0; e < 8; ++e) { aq[e] = z; ak[e] = z; av[e] = z; }

#pragma unroll
  for (int kb = 0; kb < 8; ++kb) {
#pragma unroll
    for (int e8 = 0; e8 < 8; ++e8) {
      const int wrow = (e8 * 16 + lo) * 256 + kb * 32 + hi * 8;
      half8 bq = *reinterpret_cast<const half8*>(&WT[wrow]);
      half8 bk = *reinterpret_cast<const half8*>(&WT[32768 + wrow]);
      half8 bv = *reinterpret_cast<const half8*>(&WT[65536 + wrow]);
      aq[e8] = __builtin_amdgcn_mfma_f32_16x16x32_f16(a[kb], bq, aq[e8], 0, 0, 0);
      ak[e8] = __builtin_amdgcn_mfma_f32_16x16x32_f16(a[kb], bk, ak[e8], 0, 0, 0);
      av[e8] = __builtin_amdgcn_mfma_f32_16x16x32_f16(bv, a[kb], av[e8], 0, 0, 0);
    }
  }
#pragma unroll
  for (int e8 = 0; e8 < 8; ++e8) {
#pragma unroll
    for (int i = 0; i < 4; ++i) {
      int row = qb + hi * 4 + i;
      int col = e8 * 16 + lo;
      Qb[row * 128 + col] = f2h(aq[e8][i]);
      Kb[row * 128 + col] = f2h(ak[e8][i]);
      VTb[(e8 * 16 + hi * 4 + i) * 16384 + qb + lo] = f2h(av[e8][i]);
    }
  }
}

// ---------------------------------------------------------------------------
// Kernel 2: flash attention, m214-style 32x32 swapped-QK^T structure.
// Block: 256 thr = 4 waves x 32 q-rows; KVBLK=64; NSPLIT=4 (1024 kv/block).
// In-register softmax (lane owns q=lane&31); K/V LDS XOR-swizzled;
// async reg-staging. grid = 32 qtiles x 16 (b,s) = 512 blocks.
// ---------------------------------------------------------------------------
__global__ __launch_bounds__(256, 2) void attn_split2(
    const unsigned short* __restrict__ Qb, const unsigned short* __restrict__ Kb,
    const unsigned short* __restrict__ VTb, unsigned short* __restrict__ Opart,
    float* __restrict__ ml) {
  __shared__ unsigned short K_s[64 * 128];    // 16KB, chunk16 ^= row&15
  __shared__ unsigned short V_s[128 * 128];   // 32KB (rows padded to 16 slots), chunk ^= e&15

  const int tid = threadIdx.x;
  const int wv = tid >> 6, lane = tid & 63, l31 = lane & 31, hi = lane >> 5;
  const int c = blockIdx.x & 15, t = blockIdx.x >> 4;  // XCD: c,c+8 share an XCD
  const int b = c >> 2, s = c & 3;
  const int qbw = b * 4096 + t * 128 + wv * 32;  // wave's q base
  const int kv0 = b * 4096 + s * 1024;

  // Q B-frags: lane holds Q[qbw+l31][kc*16 + hi*8 + j]
  half8 qf[8];
#pragma unroll
  for (int kc = 0; kc < 8; ++kc)
    qf[kc] = *reinterpret_cast<const half8*>(&Qb[(qbw + l31) * 128 + kc * 16 + hi * 8]);

  f32x16 acc[4];
#pragma unroll
  for (int et = 0; et < 4; ++et)
#pragma unroll
    for (int r = 0; r < 16; ++r) acc[et][r] = 0.f;

  float mraw = -INFINITY, mL = -INFINITY, lsum = 0.f;
  half8 sreg[8];

#define STAGE_LOAD(KT_) do {                                                   \
    const int kvb_ = kv0 + (KT_) * 64;                                         \
    _Pragma("unroll")                                                          \
    for (int j = 0; j < 4; ++j) {                                              \
      int g = tid + j * 256; int row = g >> 4, cc = g & 15;                    \
      sreg[j] = *reinterpret_cast<const half8*>(&Kb[(kvb_ + row) * 128 + cc * 8]); \
    }                                                                          \
    _Pragma("unroll")                                                          \
    for (int j = 0; j < 4; ++j) {                                              \
      int g = tid + j * 256; int e = g >> 3, cc = g & 7;                       \
      sreg[4 + j] = *reinterpret_cast<const half8*>(&VTb[e * 16384 + kvb_ + cc * 8]); \
    }                                                                          \
  } while (0)

#define STAGE_WRITE() do {                                                     \
    _Pragma("unroll")                                                          \
    for (int j = 0; j < 4; ++j) {                                              \
      int g = tid + j * 256; int row = g >> 4, cc = g & 15;                    \
      *reinterpret_cast<half8*>(&K_s[row * 128 + ((cc ^ (row & 15)) << 3)]) = sreg[j]; \
    }                                                                          \
    _Pragma("unroll")                                                          \
    for (int j = 0; j < 4; ++j) {                                              \
      int g = tid + j * 256; int e = g >> 3, cc = g & 7;                       \
      *reinterpret_cast<half8*>(&V_s[e * 128 + ((cc ^ (e & 15)) << 3)]) = sreg[4 + j]; \
    }                                                                          \
  } while (0)

  STAGE_LOAD(0);
  STAGE_WRITE();
  __syncthreads();

  for (int kt = 0; kt < NKT; ++kt) {
    if (kt + 1 < NKT) STAGE_LOAD(kt + 1);  // issue early; lands under compute

    // S^T[kv][q] tiles: f=0,1 (kv 0-31, 32-63)
    f32x16 sf[2];
#pragma unroll
    for (int f = 0; f < 2; ++f)
#pragma unroll
      for (int r = 0; r < 16; ++r) sf[f][r] = 0.f;
#pragma unroll
    for (int kc = 0; kc < 8; ++kc) {
#pragma unroll
      for (int f = 0; f < 2; ++f) {
        const int rk = f * 32 + l31;
        half8 kf = *reinterpret_cast<const half8*>(
            &K_s[rk * 128 + ((((kc << 1) | hi) ^ (rk & 15)) << 3)]);
        sf[f] = __builtin_amdgcn_mfma_f32_32x32x16_f16(kf, qf[kc], sf[f], 0, 0, 0);
      }
    }

    // ---- in-lane online softmax (q = l31; lane holds 32 of 64 kv) ----
    float tp[16];
#pragma unroll
    for (int r = 0; r < 16; ++r) tp[r] = fmaxf(sf[0][r], sf[1][r]);
#pragma unroll
    for (int r = 0; r < 8; ++r) tp[r] = fmaxf(tp[r], tp[r + 8]);
#pragma unroll
    for (int r = 0; r < 4; ++r) tp[r] = fmaxf(tp[r], tp[r + 4]);
    float smax = fmaxf(fmaxf(tp[0], tp[1]), fmaxf(tp[2], tp[3]));
    smax = fmaxf(smax, __shfl_xor(smax, 32, 64));
    const float mnew = fmaxf(mraw, smax);
    const float mLn = mnew * LOG2E;
    const float alpha = exp2f(mL - mLn);
#pragma unroll
    for (int f = 0; f < 2; ++f)
#pragma unroll
      for (int r = 0; r < 16; ++r)
        sf[f][r] = exp2f(__builtin_fmaf(sf[f][r], LOG2E, -mLn));
    float sp[16];
#pragma unroll
    for (int r = 0; r < 16; ++r) sp[r] = sf[0][r] + sf[1][r];
#pragma unroll
    for (int r = 0; r < 8; ++r) sp[r] = sp[r] + sp[r + 8];
#pragma unroll
    for (int r = 0; r < 4; ++r) sp[r] = sp[r] + sp[r + 4];
    float ssum = (sp[0] + sp[1]) + (sp[2] + sp[3]);
    ssum += __shfl_xor(ssum, 32, 64);
    lsum = lsum * alpha + ssum;
    mraw = mnew; mL = mLn;
#pragma unroll
    for (int et = 0; et < 4; ++et)
#pragma unroll
      for (int r = 0; r < 16; ++r) acc[et][r] *= alpha;

    // ---- PV: O^T[e][q] += V^T x P; P B-frag assembled in-register ----
#pragma unroll
    for (int f = 0; f < 2; ++f) {
#pragma unroll
      for (int hf = 0; hf < 2; ++hf) {
        const int rb = hf * 8;
        unsigned w0 = pk2(sf[f][rb + 0], sf[f][rb + 1]);
        unsigned w1 = pk2(sf[f][rb + 2], sf[f][rb + 3]);
        unsigned w2 = pk2(sf[f][rb + 4], sf[f][rb + 5]);
        unsigned w3 = pk2(sf[f][rb + 6], sf[f][rb + 7]);
        // cross-half exchange: hi=0 needs partner w0/w1 (kv 4..7); hi=1 needs w2/w3 (kv 8..11)
        unsigned cA = (unsigned)__shfl_xor((int)(hi ? w0 : w2), 32, 64);
        unsigned cB = (unsigned)__shfl_xor((int)(hi ? w1 : w3), 32, 64);
        uint4v pw;
        pw[0] = hi ? cA : w0;
        pw[1] = hi ? cB : w1;
        pw[2] = hi ? w2 : cA;
        pw[3] = hi ? w3 : cB;
        const half8 pa = __builtin_bit_cast(half8, pw);
        const int ks = f * 2 + hf;
#pragma unroll
        for (int et = 0; et < 4; ++et) {
          const int e = et * 32 + l31;
          half8 vf = *reinterpret_cast<const half8*>(
              &V_s[e * 128 + ((((ks << 1) | hi) ^ (e & 15)) << 3)]);
          acc[et] = __builtin_amdgcn_mfma_f32_32x32x16_f16(vf, pa, acc[et], 0, 0, 0);
        }
      }
    }

    __syncthreads();               // all waves done reading K_s/V_s
    if (kt + 1 < NKT) STAGE_WRITE();
    __syncthreads();               // next tile visible
  }

  // ---- epilogue: transpose O^T frag -> q-major via LDS, coalesced stores ----
  unsigned short* T = &V_s[wv * 4096];  // per-wave 8KB scratch (32 q x 128 e)
#pragma unroll
  for (int et = 0; et < 4; ++et)
#pragma unroll
    for (int r = 0; r < 16; r += 2) {
      const int e = et * 32 + (r & 3) + ((r >> 2) << 3) + (hi << 2);
      *reinterpret_cast<unsigned*>(&T[l31 * 128 + e]) = pk2(acc[et][r], acc[et][r + 1]);
    }
  __syncthreads();
#pragma unroll
  for (int j = 0; j < 8; ++j) {
    const int cgq = lane + j * 64;
    const int q = cgq >> 4, cc = cgq & 15;
    const int grow = qbw + q;
    const int prow = (((grow >> 6) << 2) + s) * 64 + (grow & 63);
    *reinterpret_cast<uint4v*>(&Opart[prow * 128 + cc * 8]) =
        *reinterpret_cast<const uint4v*>(&T[q * 128 + cc * 8]);
  }
  if (hi == 0) {
    const int grow = qbw + l31;
    const int prow = (((grow >> 6) << 2) + s) * 64 + (grow & 63);
    f32x2 v; v[0] = mL; v[1] = lsum;  // mL is log2-domain
    *reinterpret_cast<f32x2*>(&ml[prow * 2]) = v;
  }
#undef STAGE_LOAD
#undef STAGE_WRITE
}

// ---------------------------------------------------------------------------
// Kernel 3: merge NSPLIT=4 partials (m stored in log2 domain).
// ---------------------------------------------------------------------------
__global__ __launch_bounds__(256) void merge_kernel(
    const unsigned short* __restrict__ Opart, const float* __restrict__ ml,
    float* __restrict__ out) {
  int idx = blockIdx.x * 256 + threadIdx.x;  // 2097152
  int r = idx >> 7, col = idx & 127;
  int qt = r >> 6, rl = r & 63;
  float mm[4], ll[4];
#pragma unroll
  for (int s = 0; s < 4; ++s) {
    f32x2 v = *reinterpret_cast<const f32x2*>(&ml[((qt * 4 + s) * 64 + rl) * 2]);
    mm[s] = v[0]; ll[s] = v[1];
  }
  float M = fmaxf(fmaxf(mm[0], mm[1]), fmaxf(mm[2], mm[3]));
  float L = 0.f, o = 0.f;
#pragma unroll
  for (int s = 0; s < 4; ++s) {
    float w = exp2f(mm[s] - M);
    L += w * ll[s];
    o += w * h2f(Opart[((qt * 4 + s) * 64 + rl) * 128 + col]);
  }
  out[r * 128 + col] = o / L;
}

// ---------------------------------------------------------------------------
extern "C" void kernel_launch(void* const* d_in, const int* in_sizes, int n_in,
                              void* d_out, int out_size, void* d_ws, size_t ws_size,
                              hipStream_t stream) {
  const float* seq = (const float*)d_in[0];
  // d_in[1] = lengths: UNUSED by the reference (no masking).
  const float* Wq = (const float*)d_in[2];
  const float* Wk = (const float*)d_in[3];
  const float* Wv = (const float*)d_in[4];
  float* out = (float*)d_out;

  unsigned short* WT  = (unsigned short*)d_ws;
  unsigned short* Qb  = WT + 3 * 128 * 256;
  unsigned short* Kb  = Qb + 16384 * 128;
  unsigned short* VTb = Kb + 16384 * 128;
  unsigned short* Opart = VTb + 16384 * 128;          // 16384*4*128 halfs
  float* ml = (float*)(Opart + 16384 * 4 * 128);      // 65536 float2

  pack_w<<<384, 256, 0, stream>>>(Wq, Wk, Wv, WT);
  proj1<<<1024, 64, 0, stream>>>(seq, WT, Qb, Kb, VTb);
  attn_split2<<<512, 256, 0, stream>>>(Qb, Kb, VTb, Opart, ml);
  merge_kernel<<<8192, 256, 0, stream>>>(Opart, ml, out);
}